// Round 1
// baseline (10027.039 us; speedup 1.0000x reference)
//
#include <hip/hip_runtime.h>

// Swin block: B=64, H=W=56, C=96, nh=3, d=32, WS=7, SS=3, N=49, nW=64.
constexpr int C_   = 96;
constexpr int NH   = 3;
constexpr int DH   = 32;
constexpr int NTOK = 49;    // tokens per window
constexpr int HW   = 56;
constexpr int FF   = 384;   // 4*C

__device__ __forceinline__ float wave_sum(float v) {
  #pragma unroll
  for (int off = 32; off; off >>= 1) v += __shfl_down(v, off);
  return __shfl(v, 0);
}
__device__ __forceinline__ float wave_max(float v) {
  #pragma unroll
  for (int off = 32; off; off >>= 1) v = fmaxf(v, __shfl_down(v, off));
  return __shfl(v, 0);
}

// One block per window-batch (bw = b*64 + widx). Fused:
// gather(+roll) -> LN1 -> QKV -> per-head attn(bias+mask+softmax) -> PV -> proj -> +residual
__global__ __launch_bounds__(256) void swin_attn_kernel(
    const float* __restrict__ x,          // [B, 3136, 96]
    const float* __restrict__ attn_mask,  // [64, 49, 49]
    const int*   __restrict__ rel_index,  // [49*49]
    const float* __restrict__ n1g, const float* __restrict__ n1b,
    const float* __restrict__ qkv_w,      // [288, 96]
    const float* __restrict__ qkv_b,      // [288]
    const float* __restrict__ rel_tab,    // [169, 3]
    const float* __restrict__ proj_w,     // [96, 96]
    const float* __restrict__ proj_b,     // [96]
    float* __restrict__ out)              // [B, 3136, 96]  (x + attn-path)
{
  __shared__ float s_xo[NTOK][C_];              // LN'd x, later attn output
  __shared__ float s_qkv[3][NH][NTOK][DH + 1];  // +1 pad: conflict-free column reads
  __shared__ float s_attn[NTOK][NTOK];

  const int tid  = threadIdx.x;
  const int wv   = tid >> 6, lane = tid & 63;
  const int bw   = blockIdx.x;
  const int b    = bw >> 6, widx = bw & 63;
  const int wr   = widx >> 3, wc = widx & 7;

  // ---- stage 1: gather (shifted) + LayerNorm1 ----
  for (int n = wv; n < NTOK; n += 4) {
    int i = n / 7, j = n - i * 7;
    int h = wr * 7 + i + 3; if (h >= HW) h -= HW;   // roll(-3) => read (hs+3)%56
    int w = wc * 7 + j + 3; if (w >= HW) w -= HW;
    const float* src = x + ((size_t)b * (HW * HW) + (size_t)h * HW + w) * C_;
    float v0 = src[lane];
    float v1 = (lane < 32) ? src[64 + lane] : 0.f;
    float s  = wave_sum(v0 + v1);
    float ss = wave_sum(v0 * v0 + v1 * v1);
    float mean = s * (1.f / 96.f);
    float var  = ss * (1.f / 96.f) - mean * mean;
    float inv  = rsqrtf(var + 1e-5f);
    s_xo[n][lane] = (v0 - mean) * inv * n1g[lane] + n1b[lane];
    if (lane < 32)
      s_xo[n][64 + lane] = (v1 - mean) * inv * n1g[64 + lane] + n1b[64 + lane];
  }
  __syncthreads();

  // ---- stage 2: QKV GEMM (49x96 @ 96x288) ----
  for (int idx = tid; idx < NTOK * 288; idx += 256) {
    int n = idx / 288, o = idx - n * 288;
    const float4* wrow = (const float4*)(qkv_w + o * C_);
    const float4* xv   = (const float4*)(s_xo[n]);
    float a = qkv_b[o];
    #pragma unroll
    for (int c = 0; c < 24; c++) {
      float4 w4 = wrow[c], x4 = xv[c];
      a += w4.x * x4.x + w4.y * x4.y + w4.z * x4.z + w4.w * x4.w;
    }
    int which = o / 96, r = o - which * 96;
    int hh = r >> 5, dd = r & 31;
    if (which == 0) a *= 0.17677669529663687f;  // d^-0.5
    s_qkv[which][hh][n][dd] = a;
  }
  __syncthreads();

  // ---- stage 3: per-head attention ----
  for (int hh = 0; hh < NH; hh++) {
    for (int idx = tid; idx < NTOK * NTOK; idx += 256) {
      int n = idx / NTOK, m = idx - n * NTOK;
      const float* qn = s_qkv[0][hh][n];
      const float* km = s_qkv[1][hh][m];
      float a = 0.f;
      #pragma unroll
      for (int dd = 0; dd < DH; dd++) a += qn[dd] * km[dd];
      a += rel_tab[rel_index[idx] * NH + hh];
      a += attn_mask[((size_t)widx * NTOK + n) * NTOK + m];
      s_attn[n][m] = a;
    }
    __syncthreads();
    for (int n = wv; n < NTOK; n += 4) {
      float v  = (lane < NTOK) ? s_attn[n][lane] : -3.4e38f;
      float mx = wave_max(v);
      float e  = (lane < NTOK) ? __expf(v - mx) : 0.f;
      float sum = wave_sum(e);
      if (lane < NTOK) s_attn[n][lane] = e / sum;
    }
    __syncthreads();
    for (int idx = tid; idx < NTOK * DH; idx += 256) {
      int n = idx >> 5, dd = idx & 31;
      float a = 0.f;
      #pragma unroll
      for (int m = 0; m < NTOK; m++) a += s_attn[n][m] * s_qkv[2][hh][m][dd];
      s_xo[n][hh * DH + dd] = a;   // s_xo reused as attn output
    }
    __syncthreads();
  }

  // ---- stage 4: projection + residual scatter (same index map as gather) ----
  for (int idx = tid; idx < NTOK * C_; idx += 256) {
    int n = idx / C_, c = idx - n * C_;
    const float4* wrow = (const float4*)(proj_w + c * C_);
    const float4* ov   = (const float4*)(s_xo[n]);
    float a = proj_b[c];
    #pragma unroll
    for (int cc = 0; cc < 24; cc++) {
      float4 w4 = wrow[cc], o4 = ov[cc];
      a += w4.x * o4.x + w4.y * o4.y + w4.z * o4.z + w4.w * o4.w;
    }
    int i = n / 7, j = n - i * 7;
    int h = wr * 7 + i + 3; if (h >= HW) h -= HW;
    int w = wc * 7 + j + 3; if (w >= HW) w -= HW;
    size_t off = ((size_t)b * (HW * HW) + (size_t)h * HW + w) * C_ + c;
    out[off] = x[off] + a;
  }
}

// MLP: LN2 -> fc1(96->384)+GELU(exact) -> fc2(384->96) -> +residual.  In-place on out.
constexpr int TPB = 8;  // tokens per block
__global__ __launch_bounds__(256) void swin_mlp_kernel(
    const float* __restrict__ xin,   // residual stream (= out buffer)
    float* __restrict__ xout,
    const float* __restrict__ n2g, const float* __restrict__ n2b,
    const float* __restrict__ fc1_w, const float* __restrict__ fc1_b,
    const float* __restrict__ fc2_w, const float* __restrict__ fc2_b,
    long long total)
{
  __shared__ float s_raw[TPB][C_];
  __shared__ float s_n[TPB][C_];
  __shared__ float s_h[TPB][FF];
  const int tid = threadIdx.x, wv = tid >> 6, lane = tid & 63;
  const long long t0 = (long long)blockIdx.x * TPB;

  for (int t = wv; t < TPB; t += 4) {
    long long tok = t0 + t;
    if (tok >= total) continue;
    const float* src = xin + tok * C_;
    float v0 = src[lane];
    float v1 = (lane < 32) ? src[64 + lane] : 0.f;
    float s  = wave_sum(v0 + v1);
    float ss = wave_sum(v0 * v0 + v1 * v1);
    float mean = s * (1.f / 96.f);
    float inv  = rsqrtf(ss * (1.f / 96.f) - mean * mean + 1e-5f);
    s_raw[t][lane] = v0;
    s_n[t][lane]   = (v0 - mean) * inv * n2g[lane] + n2b[lane];
    if (lane < 32) {
      s_raw[t][64 + lane] = v1;
      s_n[t][64 + lane]   = (v1 - mean) * inv * n2g[64 + lane] + n2b[64 + lane];
    }
  }
  __syncthreads();

  for (int idx = tid; idx < TPB * FF; idx += 256) {
    int t = idx / FF, o = idx - t * FF;
    const float4* wrow = (const float4*)(fc1_w + o * C_);
    const float4* xv   = (const float4*)(s_n[t]);
    float a = fc1_b[o];
    #pragma unroll
    for (int c = 0; c < 24; c++) {
      float4 w4 = wrow[c], x4 = xv[c];
      a += w4.x * x4.x + w4.y * x4.y + w4.z * x4.z + w4.w * x4.w;
    }
    // exact GELU: 0.5*x*(1+erf(x/sqrt(2)))
    s_h[t][o] = 0.5f * a * (1.f + erff(a * 0.70710678118654752f));
  }
  __syncthreads();

  for (int idx = tid; idx < TPB * C_; idx += 256) {
    int t = idx / C_, o = idx - t * C_;
    long long tok = t0 + t;
    if (tok >= total) continue;
    const float4* wrow = (const float4*)(fc2_w + o * FF);
    const float4* hv   = (const float4*)(s_h[t]);
    float a = fc2_b[o];
    #pragma unroll 8
    for (int c = 0; c < 96; c++) {
      float4 w4 = wrow[c], h4 = hv[c];
      a += w4.x * h4.x + w4.y * h4.y + w4.z * h4.z + w4.w * h4.w;
    }
    xout[tok * C_ + o] = s_raw[t][o] + a;
  }
}

extern "C" void kernel_launch(void* const* d_in, const int* in_sizes, int n_in,
                              void* d_out, int out_size, void* d_ws, size_t ws_size,
                              hipStream_t stream) {
  const float* x         = (const float*)d_in[0];
  const float* attn_mask = (const float*)d_in[1];
  const int*   rel_index = (const int*)  d_in[2];
  const float* n1g       = (const float*)d_in[3];
  const float* n1b       = (const float*)d_in[4];
  const float* qkv_w     = (const float*)d_in[5];
  const float* qkv_b     = (const float*)d_in[6];
  const float* rel_tab   = (const float*)d_in[7];
  const float* proj_w    = (const float*)d_in[8];
  const float* proj_b    = (const float*)d_in[9];
  const float* n2g       = (const float*)d_in[10];
  const float* n2b       = (const float*)d_in[11];
  const float* fc1_w     = (const float*)d_in[12];
  const float* fc1_b     = (const float*)d_in[13];
  const float* fc2_w     = (const float*)d_in[14];
  const float* fc2_b     = (const float*)d_in[15];
  float* out = (float*)d_out;

  const int B = in_sizes[0] / (HW * HW * C_);
  const long long total = (long long)B * HW * HW;

  swin_attn_kernel<<<B * 64, 256, 0, stream>>>(
      x, attn_mask, rel_index, n1g, n1b, qkv_w, qkv_b, rel_tab, proj_w, proj_b, out);

  const int mblk = (int)((total + TPB - 1) / TPB);
  swin_mlp_kernel<<<mblk, 256, 0, stream>>>(
      out, out, n2g, n2b, fc1_w, fc1_b, fc2_w, fc2_b, total);
}

// Round 3
// 5983.813 us; speedup vs baseline: 1.6757x; 1.6757x over previous
//
#include <hip/hip_runtime.h>

// Swin block fully fused: B=64, H=W=56, C=96, nh=3, d=32, WS=7, SS=3, N=49, nW=64.
constexpr int C_   = 96;
constexpr int NH   = 3;
constexpr int DH   = 32;
constexpr int NTOK = 49;    // tokens per window
constexpr int HW   = 56;
constexpr int FF   = 384;   // 4*C
constexpr int PAD  = 101;   // s_buf row stride (101%32=5, coprime with 32)
constexpr int P2   = 97;    // stage-B row stride (97%32=1 -> 2-way max, free)

__device__ __forceinline__ float wave_sum(float v) {
  #pragma unroll
  for (int off = 32; off; off >>= 1) v += __shfl_down(v, off);
  return __shfl(v, 0);
}
__device__ __forceinline__ float wave_max(float v) {
  #pragma unroll
  for (int off = 32; off; off >>= 1) v = fmaxf(v, __shfl_down(v, off));
  return __shfl(v, 0);
}

// One block per window (bw = b*64 + widx). Entire Swin block in one kernel:
// gather(+roll)+LN1 -> QKV -> attn(bias+mask+softmax) -> proj -> y=x+attn
// -> LN2 -> fc1+GELU -> fc2 -> out = y + mlp.  One coalesced store at the end.
__global__ __launch_bounds__(256) void swin_block_kernel(
    const float* __restrict__ x,          // [B, 3136, 96]
    const float* __restrict__ attn_mask,  // [64, 49, 49]
    const int*   __restrict__ rel_index,  // [49*49]
    const float* __restrict__ n1g, const float* __restrict__ n1b,
    const float* __restrict__ qkv_w,      // [288, 96]
    const float* __restrict__ qkv_b,      // [288]
    const float* __restrict__ rel_tab,    // [169, 3]
    const float* __restrict__ proj_w,     // [96, 96]
    const float* __restrict__ proj_b,     // [96]
    const float* __restrict__ n2g, const float* __restrict__ n2b,
    const float* __restrict__ fc1_w,      // [384, 96]
    const float* __restrict__ fc1_b,      // [384]
    const float* __restrict__ fc2_w,      // [96, 384]
    const float* __restrict__ fc2_b,      // [96]
    float* __restrict__ out)              // [B, 3136, 96]
{
  __shared__ float s_buf[NTOK * PAD];            // 19.8 KB: xln -> attn mat -> y
  __shared__ float s_pool[3 * NH * NTOK * (DH + 1)];  // 58.2 KB, phase-aliased
  float (*s_qkv)[NH][NTOK][DH + 1] = (float (*)[NH][NTOK][DH + 1])s_pool;
  float* s_p1 = s_pool + 4851;   // slot1: proj-out, later h-chunk   [49*97 used]
  float* s_yn = s_pool;          // slot0: LN2 output (attn-out dead by then)
  float* s_ac = s_pool + 9702;   // slot2: mlp accumulator (V dead by then)

  const int tid  = threadIdx.x;
  const int wv   = tid >> 6, lane = tid & 63;
  const int bw   = blockIdx.x;
  const int b    = bw >> 6, widx = bw & 63;
  const int wr   = widx >> 3, wc = widx & 7;

  // ---- stage 1: gather (roll -3) + LayerNorm1 -> s_buf ----
  for (int n = wv; n < NTOK; n += 4) {
    int i = n / 7, j = n - i * 7;
    int h = wr * 7 + i + 3; if (h >= HW) h -= HW;
    int w = wc * 7 + j + 3; if (w >= HW) w -= HW;
    const float* src = x + ((size_t)b * (HW * HW) + (size_t)h * HW + w) * C_;
    float v0 = src[lane];
    float v1 = (lane < 32) ? src[64 + lane] : 0.f;
    float s  = wave_sum(v0 + v1);
    float ss = wave_sum(v0 * v0 + v1 * v1);
    float mean = s * (1.f / 96.f);
    float inv  = rsqrtf(ss * (1.f / 96.f) - mean * mean + 1e-5f);
    s_buf[n * PAD + lane] = (v0 - mean) * inv * n1g[lane] + n1b[lane];
    if (lane < 32)
      s_buf[n * PAD + 64 + lane] = (v1 - mean) * inv * n1g[64 + lane] + n1b[64 + lane];
  }
  __syncthreads();

  // ---- stage 2: QKV (49x96 @ 96x288), token lane-fast, 6 outputs/thread ----
  for (int idx = tid; idx < 48 * NTOK; idx += 256) {
    int og = idx / NTOK, n = idx - og * NTOK;
    int o0 = og * 6;
    const float* xrow = s_buf + n * PAD;
    const float* w0 = qkv_w + (size_t)(o0 + 0) * C_;
    const float* w1 = qkv_w + (size_t)(o0 + 1) * C_;
    const float* w2 = qkv_w + (size_t)(o0 + 2) * C_;
    const float* w3 = qkv_w + (size_t)(o0 + 3) * C_;
    const float* w4 = qkv_w + (size_t)(o0 + 4) * C_;
    const float* w5 = qkv_w + (size_t)(o0 + 5) * C_;
    float a[6] = {0.f, 0.f, 0.f, 0.f, 0.f, 0.f};
    #pragma unroll
    for (int cc = 0; cc < C_; ++cc) {
      float xv = xrow[cc];
      a[0] += w0[cc] * xv; a[1] += w1[cc] * xv; a[2] += w2[cc] * xv;
      a[3] += w3[cc] * xv; a[4] += w4[cc] * xv; a[5] += w5[cc] * xv;
    }
    #pragma unroll
    for (int j = 0; j < 6; ++j) {
      int o = o0 + j;
      float v = a[j] + qkv_b[o];
      int which = o / 96, r = o - which * 96;
      int hh = r >> 5, dd = r & 31;
      if (which == 0) v *= 0.17677669529663687f;  // d^-0.5
      s_qkv[which][hh][n][dd] = v;
    }
  }
  __syncthreads();

  // ---- stage 3: per-head attention (attn matrix in s_buf, out into Q slices) ----
  for (int hh = 0; hh < NH; hh++) {
    for (int idx = tid; idx < NTOK * NTOK; idx += 256) {
      int n = idx / NTOK, m = idx - n * NTOK;
      const float* qn = s_qkv[0][hh][n];
      const float* km = s_qkv[1][hh][m];
      float a = 0.f;
      #pragma unroll
      for (int dd = 0; dd < DH; dd++) a += qn[dd] * km[dd];
      a += rel_tab[rel_index[idx] * NH + hh];
      a += attn_mask[((size_t)widx * NTOK + n) * NTOK + m];
      s_buf[n * NTOK + m] = a;
    }
    __syncthreads();
    for (int n = wv; n < NTOK; n += 4) {
      float v  = (lane < NTOK) ? s_buf[n * NTOK + lane] : -3.4e38f;
      float mx = wave_max(v);
      float e  = (lane < NTOK) ? __expf(v - mx) : 0.f;
      float sum = wave_sum(e);
      if (lane < NTOK) s_buf[n * NTOK + lane] = e / sum;
    }
    __syncthreads();
    for (int idx = tid; idx < NTOK * DH; idx += 256) {
      int n = idx >> 5, dd = idx & 31;
      float a = 0.f;
      #pragma unroll
      for (int m = 0; m < NTOK; m++) a += s_buf[n * NTOK + m] * s_qkv[2][hh][m][dd];
      s_qkv[0][hh][n][dd] = a;   // attn-out into dead Q slice
    }
    __syncthreads();
  }

  // ---- stage 4: projection -> s_p1 (stride P2) ----
  for (int idx = tid; idx < 16 * NTOK; idx += 256) {
    int og = idx / NTOK, n = idx - og * NTOK;
    int c0 = og * 6;
    const float* p0 = proj_w + (size_t)(c0 + 0) * C_;
    const float* p1 = proj_w + (size_t)(c0 + 1) * C_;
    const float* p2 = proj_w + (size_t)(c0 + 2) * C_;
    const float* p3 = proj_w + (size_t)(c0 + 3) * C_;
    const float* p4 = proj_w + (size_t)(c0 + 4) * C_;
    const float* p5 = proj_w + (size_t)(c0 + 5) * C_;
    float a[6] = {0.f, 0.f, 0.f, 0.f, 0.f, 0.f};
    #pragma unroll
    for (int cc = 0; cc < C_; ++cc) {
      float av = s_qkv[0][cc >> 5][n][cc & 31];
      a[0] += p0[cc] * av; a[1] += p1[cc] * av; a[2] += p2[cc] * av;
      a[3] += p3[cc] * av; a[4] += p4[cc] * av; a[5] += p5[cc] * av;
    }
    #pragma unroll
    for (int j = 0; j < 6; ++j)
      s_p1[n * P2 + c0 + j] = a[j] + proj_b[c0 + j];
  }
  __syncthreads();

  // ---- stage 5: y = x + proj  (coalesced x re-read) -> s_buf ----
  for (int idx = tid; idx < NTOK * C_; idx += 256) {
    int n = idx / C_, c = idx - n * C_;
    int i = n / 7, j = n - i * 7;
    int h = wr * 7 + i + 3; if (h >= HW) h -= HW;
    int w = wc * 7 + j + 3; if (w >= HW) w -= HW;
    size_t off = ((size_t)b * (HW * HW) + (size_t)h * HW + w) * C_ + c;
    s_buf[n * PAD + c] = x[off] + s_p1[n * P2 + c];
  }
  __syncthreads();

  // ---- stage 6: LN2 -> s_yn ; acc init = y + fc2_b -> s_ac ----
  for (int n = wv; n < NTOK; n += 4) {
    float v0 = s_buf[n * PAD + lane];
    float v1 = (lane < 32) ? s_buf[n * PAD + 64 + lane] : 0.f;
    float s  = wave_sum(v0 + v1);
    float ss = wave_sum(v0 * v0 + v1 * v1);
    float mean = s * (1.f / 96.f);
    float inv  = rsqrtf(ss * (1.f / 96.f) - mean * mean + 1e-5f);
    s_yn[n * P2 + lane] = (v0 - mean) * inv * n2g[lane] + n2b[lane];
    s_ac[n * P2 + lane] = v0 + fc2_b[lane];
    if (lane < 32) {
      s_yn[n * P2 + 64 + lane] = (v1 - mean) * inv * n2g[64 + lane] + n2b[64 + lane];
      s_ac[n * P2 + 64 + lane] = v1 + fc2_b[64 + lane];
    }
  }
  __syncthreads();

  // ---- stage 7: MLP in 4 chunks of 96 hidden units ----
  for (int k = 0; k < 4; ++k) {
    // 7a: h = gelu(fc1[k*96 .. k*96+95] . yn) -> s_p1
    for (int idx = tid; idx < 16 * NTOK; idx += 256) {
      int og = idx / NTOK, n = idx - og * NTOK;
      int o0 = k * 96 + og * 6;
      const float* yrow = s_yn + n * P2;
      const float* w0 = fc1_w + (size_t)(o0 + 0) * C_;
      const float* w1 = fc1_w + (size_t)(o0 + 1) * C_;
      const float* w2 = fc1_w + (size_t)(o0 + 2) * C_;
      const float* w3 = fc1_w + (size_t)(o0 + 3) * C_;
      const float* w4 = fc1_w + (size_t)(o0 + 4) * C_;
      const float* w5 = fc1_w + (size_t)(o0 + 5) * C_;
      float a[6] = {0.f, 0.f, 0.f, 0.f, 0.f, 0.f};
      #pragma unroll
      for (int cc = 0; cc < C_; ++cc) {
        float yv = yrow[cc];
        a[0] += w0[cc] * yv; a[1] += w1[cc] * yv; a[2] += w2[cc] * yv;
        a[3] += w3[cc] * yv; a[4] += w4[cc] * yv; a[5] += w5[cc] * yv;
      }
      #pragma unroll
      for (int j = 0; j < 6; ++j) {
        float ho = a[j] + fc1_b[o0 + j];
        ho = 0.5f * ho * (1.f + erff(ho * 0.70710678118654752f));  // exact GELU
        s_p1[n * P2 + og * 6 + j] = ho;
      }
    }
    __syncthreads();
    // 7b: acc += h . fc2_w[:, k*96 .. k*96+95]^T
    for (int idx = tid; idx < 16 * NTOK; idx += 256) {
      int og = idx / NTOK, n = idx - og * NTOK;
      int c0 = og * 6;
      const float* hrow = s_p1 + n * P2;
      const float* w0 = fc2_w + (size_t)(c0 + 0) * FF + k * 96;
      const float* w1 = fc2_w + (size_t)(c0 + 1) * FF + k * 96;
      const float* w2 = fc2_w + (size_t)(c0 + 2) * FF + k * 96;
      const float* w3 = fc2_w + (size_t)(c0 + 3) * FF + k * 96;
      const float* w4 = fc2_w + (size_t)(c0 + 4) * FF + k * 96;
      const float* w5 = fc2_w + (size_t)(c0 + 5) * FF + k * 96;
      float a[6] = {0.f, 0.f, 0.f, 0.f, 0.f, 0.f};
      #pragma unroll
      for (int cc = 0; cc < 96; ++cc) {
        float hv = hrow[cc];
        a[0] += w0[cc] * hv; a[1] += w1[cc] * hv; a[2] += w2[cc] * hv;
        a[3] += w3[cc] * hv; a[4] += w4[cc] * hv; a[5] += w5[cc] * hv;
      }
      #pragma unroll
      for (int j = 0; j < 6; ++j)
        s_ac[n * P2 + c0 + j] += a[j];
    }
    __syncthreads();
  }

  // ---- stage 8: final coalesced store ----
  for (int idx = tid; idx < NTOK * C_; idx += 256) {
    int n = idx / C_, c = idx - n * C_;
    int i = n / 7, j = n - i * 7;
    int h = wr * 7 + i + 3; if (h >= HW) h -= HW;
    int w = wc * 7 + j + 3; if (w >= HW) w -= HW;
    size_t off = ((size_t)b * (HW * HW) + (size_t)h * HW + w) * C_ + c;
    out[off] = s_ac[n * P2 + c];
  }
}

extern "C" void kernel_launch(void* const* d_in, const int* in_sizes, int n_in,
                              void* d_out, int out_size, void* d_ws, size_t ws_size,
                              hipStream_t stream) {
  const float* x         = (const float*)d_in[0];
  const float* attn_mask = (const float*)d_in[1];
  const int*   rel_index = (const int*)  d_in[2];
  const float* n1g       = (const float*)d_in[3];
  const float* n1b       = (const float*)d_in[4];
  const float* qkv_w     = (const float*)d_in[5];
  const float* qkv_b     = (const float*)d_in[6];
  const float* rel_tab   = (const float*)d_in[7];
  const float* proj_w    = (const float*)d_in[8];
  const float* proj_b    = (const float*)d_in[9];
  const float* n2g       = (const float*)d_in[10];
  const float* n2b       = (const float*)d_in[11];
  const float* fc1_w     = (const float*)d_in[12];
  const float* fc1_b     = (const float*)d_in[13];
  const float* fc2_w     = (const float*)d_in[14];
  const float* fc2_b     = (const float*)d_in[15];
  float* out = (float*)d_out;

  const int B = in_sizes[0] / (HW * HW * C_);

  swin_block_kernel<<<B * 64, 256, 0, stream>>>(
      x, attn_mask, rel_index, n1g, n1b, qkv_w, qkv_b, rel_tab, proj_w, proj_b,
      n2g, n2b, fc1_w, fc1_b, fc2_w, fc2_b, out);
}

// Round 4
// 781.475 us; speedup vs baseline: 12.8309x; 7.6571x over previous
//
#include <hip/hip_runtime.h>
#include <hip/hip_bf16.h>

// Swin block fully fused, bf16 MFMA. B=64, H=W=56, C=96, nh=3, d=32, WS=7, SS=3, N=49, nW=64.
typedef __attribute__((ext_vector_type(8))) short short8;  // 8 bf16 = one A/B frag
typedef __attribute__((ext_vector_type(4))) float f32x4;   // C/D frag

constexpr int HW = 56;

// LDS pool offsets (bf16 elements). All frag-read bases are 16B-aligned.
constexpr int SX = 104;                    // stride for [64][96]-ish rows
constexpr int SQ = 40;                     // stride for [64][32] q/k rows
constexpr int SV = 72;                     // stride for vT [32][64] rows
constexpr int SP = 72;                     // stride for P [64][64] rows
constexpr int OFF_X = 0;                   // [64][SX]: xln ; later fc1 h-chunk
constexpr int OFF_Q = 64 * SX;             // [3][64][SQ]: q ; later attn-out (per-head)
constexpr int OFF_K = OFF_Q + 3 * 64 * SQ; // [3][64][SQ]: k ; later yn [64][SX]
constexpr int OFF_V = OFF_K + 3 * 64 * SQ; // [3][32][SV]: v transposed
constexpr int OFF_P = OFF_V + 3 * 32 * SV; // [64][SP]: softmax probs (one head)
constexpr int POOLN = OFF_P + 64 * SP;     // 33536 elems = 67 KB

__device__ __forceinline__ ushort bfc(float f) {
  union { __hip_bfloat16 h; ushort u; } v;
  v.h = __float2bfloat16(f);
  return v.u;
}
// 8 consecutive f32 (16B-aligned) -> bf16x8 frag
__device__ __forceinline__ short8 ldw8(const float* p) {
  float4 a = *(const float4*)p;
  float4 b = *(const float4*)(p + 4);
  short8 r;
  r[0] = (short)bfc(a.x); r[1] = (short)bfc(a.y); r[2] = (short)bfc(a.z); r[3] = (short)bfc(a.w);
  r[4] = (short)bfc(b.x); r[5] = (short)bfc(b.y); r[6] = (short)bfc(b.z); r[7] = (short)bfc(b.w);
  return r;
}
__device__ __forceinline__ float wave_sum(float v) {
  #pragma unroll
  for (int off = 32; off; off >>= 1) v += __shfl_down(v, off);
  return __shfl(v, 0);
}

__global__ __launch_bounds__(256) void swin_mfma_kernel(
    const float* __restrict__ x,          // [B,3136,96]
    const float* __restrict__ attn_mask,  // [64,49,49]
    const int*   __restrict__ rel_index,  // [2401]
    const float* __restrict__ n1g, const float* __restrict__ n1b,
    const float* __restrict__ qkv_w,      // [288,96]
    const float* __restrict__ qkv_b,      // [288]
    const float* __restrict__ rel_tab,    // [169,3]
    const float* __restrict__ proj_w,     // [96,96]
    const float* __restrict__ proj_b,     // [96]
    const float* __restrict__ n2g, const float* __restrict__ n2b,
    const float* __restrict__ fc1_w,      // [384,96]
    const float* __restrict__ fc1_b,      // [384]
    const float* __restrict__ fc2_w,      // [96,384]
    const float* __restrict__ fc2_b,      // [96]
    float* __restrict__ out)              // [B,3136,96]
{
  __shared__ short pool[POOLN];

  const int tid  = threadIdx.x;
  const int wv   = tid >> 6;          // wave id = query/token 16-row strip
  const int lane = tid & 63;
  const int ln   = lane & 15;         // frag row/col index
  const int gq   = lane >> 4;         // frag k-group
  const int bw   = blockIdx.x;
  const int b    = bw >> 6, widx = bw & 63;
  const int wr   = widx >> 3, wc = widx & 7;

  const f32x4 zf = {0.f, 0.f, 0.f, 0.f};
  const int qrow = 16 * wv + ln;      // A-frag row for this wave's strip

  // gathered (rolled) global base offset for token n in this window
  auto gbase = [&](int n) -> size_t {
    int i = n / 7, j = n - 7 * i;
    int h = wr * 7 + i + 3; if (h >= HW) h -= HW;
    int w = wc * 7 + j + 3; if (w >= HW) w -= HW;
    return ((size_t)b * (HW * HW) + (size_t)h * HW + w) * 96;
  };

  // ---- stage 1: gather + LN1 -> xln (bf16), zero pad rows 49..63 ----
  for (int n = wv; n < 49; n += 4) {
    const float* src = x + gbase(n);
    float v0 = src[lane];
    float v1 = (lane < 32) ? src[64 + lane] : 0.f;
    float s  = wave_sum(v0 + v1);
    float ss = wave_sum(v0 * v0 + v1 * v1);
    float mean = s * (1.f / 96.f);
    float inv  = rsqrtf(ss * (1.f / 96.f) - mean * mean + 1e-5f);
    pool[OFF_X + n * SX + lane] = (short)bfc((v0 - mean) * inv * n1g[lane] + n1b[lane]);
    if (lane < 32)
      pool[OFF_X + n * SX + 64 + lane] =
          (short)bfc((v1 - mean) * inv * n1g[64 + lane] + n1b[64 + lane]);
  }
  for (int idx = tid; idx < 15 * 96; idx += 256) {
    int rr = idx / 96, c = idx - 96 * rr;
    pool[OFF_X + (49 + rr) * SX + c] = 0;
  }
  __syncthreads();

  // ---- stage 2: QKV = xln @ qkv_w^T + b.  N-split: wave w owns tiles t = w, w+4, ... ----
  {
    short8 af[3][4];
    #pragma unroll
    for (int s = 0; s < 3; ++s)
      #pragma unroll
      for (int m = 0; m < 4; ++m)
        af[s][m] = *(const short8*)&pool[OFF_X + (16 * m + ln) * SX + 32 * s + 8 * gq];

    for (int t = wv; t < 18; t += 4) {
      const float* wbase = qkv_w + (size_t)(16 * t + ln) * 96;
      short8 bw3[3];
      #pragma unroll
      for (int s = 0; s < 3; ++s) bw3[s] = ldw8(wbase + 32 * s + 8 * gq);
      f32x4 acc[4] = {zf, zf, zf, zf};
      #pragma unroll
      for (int m = 0; m < 4; ++m)
        #pragma unroll
        for (int s = 0; s < 3; ++s)
          acc[m] = __builtin_amdgcn_mfma_f32_16x16x32_bf16(af[s][m], bw3[s], acc[m], 0, 0, 0);

      int o = 16 * t + ln;               // output channel 0..287
      float bias = qkv_b[o];
      int which = t / 6;                 // 0=q 1=k 2=v (tile never straddles)
      int oo = o - 96 * which;
      int hh = oo >> 5, dd = oo & 31;
      #pragma unroll
      for (int m = 0; m < 4; ++m)
        #pragma unroll
        for (int r = 0; r < 4; ++r) {
          float v = acc[m][r] + bias;
          int token = 16 * m + 4 * gq + r;
          if (which == 0)
            pool[OFF_Q + hh * (64 * SQ) + token * SQ + dd] = (short)bfc(v * 0.17677669529663687f);
          else if (which == 1)
            pool[OFF_K + hh * (64 * SQ) + token * SQ + dd] = (short)bfc(v);
          else
            pool[OFF_V + hh * (32 * SV) + dd * SV + token] = (short)bfc(v);
        }
    }
  }
  __syncthreads();

  // ---- stage 3: attention, head-sequential.  wave = 16-query strip ----
  for (int h = 0; h < 3; ++h) {
    short8 aq = *(const short8*)&pool[OFF_Q + h * (64 * SQ) + qrow * SQ + 8 * gq];
    f32x4 sc[4];
    #pragma unroll
    for (int nt = 0; nt < 4; ++nt) {
      short8 bk = *(const short8*)&pool[OFF_K + h * (64 * SQ) + (16 * nt + ln) * SQ + 8 * gq];
      sc[nt] = __builtin_amdgcn_mfma_f32_16x16x32_bf16(aq, bk, zf, 0, 0, 0);
    }
    // bias + mask + softmax (row q = 16wv+4gq+r ; col k = 16nt+ln)
    float pv[4][4];
    #pragma unroll
    for (int r = 0; r < 4; ++r) {
      int q  = 16 * wv + 4 * gq + r;
      int qc = q < 49 ? q : 48;
      #pragma unroll
      for (int nt = 0; nt < 4; ++nt) {
        int k = 16 * nt + ln;
        if (k < 49) {
          int qk = qc * 49 + k;
          float bb = rel_tab[rel_index[qk] * 3 + h] + attn_mask[(size_t)widx * 2401 + qk];
          pv[r][nt] = sc[nt][r] + bb;
        } else {
          pv[r][nt] = -1e30f;
        }
      }
    }
    #pragma unroll
    for (int r = 0; r < 4; ++r) {
      float mx = fmaxf(fmaxf(pv[r][0], pv[r][1]), fmaxf(pv[r][2], pv[r][3]));
      #pragma unroll
      for (int m2 = 1; m2 < 16; m2 <<= 1) mx = fmaxf(mx, __shfl_xor(mx, m2, 64));
      float sum = 0.f;
      #pragma unroll
      for (int nt = 0; nt < 4; ++nt) { pv[r][nt] = __expf(pv[r][nt] - mx); sum += pv[r][nt]; }
      #pragma unroll
      for (int m2 = 1; m2 < 16; m2 <<= 1) sum += __shfl_xor(sum, m2, 64);
      float inv = 1.f / sum;
      int q = 16 * wv + 4 * gq + r;
      #pragma unroll
      for (int nt = 0; nt < 4; ++nt)
        pool[OFF_P + q * SP + 16 * nt + ln] = (short)bfc(pv[r][nt] * inv);
    }
    __syncthreads();

    // PV: AO[:, h*32 + d] = P @ V ; write into dead Q slice of head h
    short8 ap0 = *(const short8*)&pool[OFF_P + qrow * SP + 8 * gq];
    short8 ap1 = *(const short8*)&pool[OFF_P + qrow * SP + 32 + 8 * gq];
    #pragma unroll
    for (int nt2 = 0; nt2 < 2; ++nt2) {
      short8 bv0 = *(const short8*)&pool[OFF_V + h * (32 * SV) + (16 * nt2 + ln) * SV + 8 * gq];
      short8 bv1 = *(const short8*)&pool[OFF_V + h * (32 * SV) + (16 * nt2 + ln) * SV + 32 + 8 * gq];
      f32x4 o = __builtin_amdgcn_mfma_f32_16x16x32_bf16(ap0, bv0, zf, 0, 0, 0);
      o = __builtin_amdgcn_mfma_f32_16x16x32_bf16(ap1, bv1, o, 0, 0, 0);
      #pragma unroll
      for (int r = 0; r < 4; ++r) {
        int token = 16 * wv + 4 * gq + r;
        pool[OFF_Q + h * (64 * SQ) + token * SQ + 16 * nt2 + ln] = (short)bfc(o[r]);
      }
    }
    __syncthreads();
  }

  // ---- stage 4: proj + residual + LN2.  y kept in VGPRs ----
  float y[6][4];
  {
    short8 aa[3];
    #pragma unroll
    for (int s = 0; s < 3; ++s)
      aa[s] = *(const short8*)&pool[OFF_Q + s * (64 * SQ) + qrow * SQ + 8 * gq];
    #pragma unroll
    for (int nt = 0; nt < 6; ++nt) {
      const float* wb = proj_w + (size_t)(16 * nt + ln) * 96;
      f32x4 acc = zf;
      #pragma unroll
      for (int s = 0; s < 3; ++s)
        acc = __builtin_amdgcn_mfma_f32_16x16x32_bf16(aa[s], ldw8(wb + 32 * s + 8 * gq), acc, 0, 0, 0);
      float pb = proj_b[16 * nt + ln];
      #pragma unroll
      for (int r = 0; r < 4; ++r) y[nt][r] = acc[r] + pb;
    }
    // + residual x (gathered)
    #pragma unroll
    for (int r = 0; r < 4; ++r) {
      int token = 16 * wv + 4 * gq + r;
      if (token < 49) {
        const float* xr = x + gbase(token);
        #pragma unroll
        for (int nt = 0; nt < 6; ++nt) y[nt][r] += xr[16 * nt + ln];
      }
    }
    // LN2 per row -> yn (bf16, in dead K space, stride SX)
    float g2[6], b2[6];
    #pragma unroll
    for (int nt = 0; nt < 6; ++nt) { g2[nt] = n2g[16 * nt + ln]; b2[nt] = n2b[16 * nt + ln]; }
    #pragma unroll
    for (int r = 0; r < 4; ++r) {
      float s1 = 0.f, s2 = 0.f;
      #pragma unroll
      for (int nt = 0; nt < 6; ++nt) { s1 += y[nt][r]; s2 += y[nt][r] * y[nt][r]; }
      #pragma unroll
      for (int m2 = 1; m2 < 16; m2 <<= 1) {
        s1 += __shfl_xor(s1, m2, 64);
        s2 += __shfl_xor(s2, m2, 64);
      }
      float mean = s1 * (1.f / 96.f);
      float inv  = rsqrtf(s2 * (1.f / 96.f) - mean * mean + 1e-5f);
      int token = 16 * wv + 4 * gq + r;
      #pragma unroll
      for (int nt = 0; nt < 6; ++nt)
        pool[OFF_K + token * SX + 16 * nt + ln] =
            (short)bfc((y[nt][r] - mean) * inv * g2[nt] + b2[nt]);
    }
  }
  __syncthreads();

  // ---- stage 5: MLP, 4 chunks of 96 hidden.  h-chunk in dead X space ----
  f32x4 accO[6] = {zf, zf, zf, zf, zf, zf};
  short8 ay[3];
  #pragma unroll
  for (int s = 0; s < 3; ++s)
    ay[s] = *(const short8*)&pool[OFF_K + qrow * SX + 32 * s + 8 * gq];

  for (int cn = 0; cn < 4; ++cn) {
    #pragma unroll
    for (int nt = 0; nt < 6; ++nt) {
      const float* wb = fc1_w + (size_t)(96 * cn + 16 * nt + ln) * 96;
      f32x4 acc = zf;
      #pragma unroll
      for (int s = 0; s < 3; ++s)
        acc = __builtin_amdgcn_mfma_f32_16x16x32_bf16(ay[s], ldw8(wb + 32 * s + 8 * gq), acc, 0, 0, 0);
      float b1 = fc1_b[96 * cn + 16 * nt + ln];
      #pragma unroll
      for (int r = 0; r < 4; ++r) {
        float hv = acc[r] + b1;
        hv = 0.5f * hv * (1.f + erff(hv * 0.70710678118654752f));  // exact GELU
        int token = 16 * wv + 4 * gq + r;
        pool[OFF_X + token * SX + 16 * nt + ln] = (short)bfc(hv);
      }
    }
    __syncthreads();
    short8 ah[3];
    #pragma unroll
    for (int s = 0; s < 3; ++s)
      ah[s] = *(const short8*)&pool[OFF_X + qrow * SX + 32 * s + 8 * gq];
    #pragma unroll
    for (int nt = 0; nt < 6; ++nt) {
      const float* wb = fc2_w + (size_t)(16 * nt + ln) * 384 + 96 * cn;
      #pragma unroll
      for (int s = 0; s < 3; ++s)
        accO[nt] = __builtin_amdgcn_mfma_f32_16x16x32_bf16(ah[s], ldw8(wb + 32 * s + 8 * gq), accO[nt], 0, 0, 0);
    }
    __syncthreads();
  }

  // ---- stage 6: out = y + mlp + fc2_b ----
  float fb[6];
  #pragma unroll
  for (int nt = 0; nt < 6; ++nt) fb[nt] = fc2_b[16 * nt + ln];
  #pragma unroll
  for (int r = 0; r < 4; ++r) {
    int token = 16 * wv + 4 * gq + r;
    if (token < 49) {
      float* dst = out + gbase(token);
      #pragma unroll
      for (int nt = 0; nt < 6; ++nt)
        dst[16 * nt + ln] = y[nt][r] + accO[nt][r] + fb[nt];
    }
  }
}

extern "C" void kernel_launch(void* const* d_in, const int* in_sizes, int n_in,
                              void* d_out, int out_size, void* d_ws, size_t ws_size,
                              hipStream_t stream) {
  const float* x         = (const float*)d_in[0];
  const float* attn_mask = (const float*)d_in[1];
  const int*   rel_index = (const int*)  d_in[2];
  const float* n1g       = (const float*)d_in[3];
  const float* n1b       = (const float*)d_in[4];
  const float* qkv_w     = (const float*)d_in[5];
  const float* qkv_b     = (const float*)d_in[6];
  const float* rel_tab   = (const float*)d_in[7];
  const float* proj_w    = (const float*)d_in[8];
  const float* proj_b    = (const float*)d_in[9];
  const float* n2g       = (const float*)d_in[10];
  const float* n2b       = (const float*)d_in[11];
  const float* fc1_w     = (const float*)d_in[12];
  const float* fc1_b     = (const float*)d_in[13];
  const float* fc2_w     = (const float*)d_in[14];
  const float* fc2_b     = (const float*)d_in[15];
  float* out = (float*)d_out;

  const int B = in_sizes[0] / (HW * HW * 96);

  swin_mfma_kernel<<<B * 64, 256, 0, stream>>>(
      x, attn_mask, rel_index, n1g, n1b, qkv_w, qkv_b, rel_tab, proj_w, proj_b,
      n2g, n2b, fc1_w, fc1_b, fc2_w, fc2_b, out);
}

// Round 5
// 296.431 us; speedup vs baseline: 33.8259x; 2.6363x over previous
//
#include <hip/hip_runtime.h>
#include <hip/hip_bf16.h>

// Swin block fully fused, bf16 MFMA. B=64, H=W=56, C=96, nh=3, d=32, WS=7, SS=3, N=49, nW=64.
typedef __attribute__((ext_vector_type(8))) short short8;  // 8 bf16 = one A/B frag
typedef __attribute__((ext_vector_type(4))) float f32x4;   // C/D frag

constexpr int HW = 56;

// ---- LDS pool (bf16 elements). All frag-read bases 16B-aligned. ----
constexpr int SR    = 104;             // row stride for [64][96] token-major buffers
constexpr int SVT   = 200;             // row stride for vT [32][3*64]
constexpr int OFF_X = 0;               // [64][SR]: xln -> P (softmax) -> fc1 h-chunk
constexpr int OFF_Q = 64 * SR;         // [64][SR]: q (cols h*32+d) -> attn-out
constexpr int OFF_K = 2 * 64 * SR;     // [64][SR]: k -> yn (LN2 out)
constexpr int OFF_V = 3 * 64 * SR;     // [32][SVT]: v^T (row d, col h*64+tok)
constexpr int POOLN = OFF_V + 32 * SVT;  // 26368 shorts = 52736 B -> 3 blocks/CU

// ---- d_ws layout (bf16 elements), frag-major: [(tile*3+s)*64 + lane]*8 + j ----
constexpr int WQKV  = 0;               // 18 tiles * 3 * 512
constexpr int WPROJ = 27648;           // 6 tiles
constexpr int WFC1  = 36864;           // 24 tiles (tile = 6*cn + nt)
constexpr int WFC2  = 73728;           // 24 tiles (tile = nt*4 + cn)
constexpr int WTOT  = 110592;          // *2B = 221184 bytes

__device__ __forceinline__ ushort bfc(float f) {
  union { __hip_bfloat16 h; ushort u; } v;
  v.h = __float2bfloat16(f);
  return v.u;
}
// fallback: 8 consecutive f32 -> bf16x8 frag (in-kernel cvt)
__device__ __forceinline__ short8 ldw8(const float* p) {
  float4 a = *(const float4*)p;
  float4 b = *(const float4*)(p + 4);
  short8 r;
  r[0] = (short)bfc(a.x); r[1] = (short)bfc(a.y); r[2] = (short)bfc(a.z); r[3] = (short)bfc(a.w);
  r[4] = (short)bfc(b.x); r[5] = (short)bfc(b.y); r[6] = (short)bfc(b.z); r[7] = (short)bfc(b.w);
  return r;
}
template<bool PRE>
__device__ __forceinline__ short8 wfrag(const short* wsb, int ts, int lane, const float* fsrc) {
  if constexpr (PRE) return *(const short8*)&wsb[(ts << 9) + lane * 8];
  else               return ldw8(fsrc);
}
__device__ __forceinline__ float wave_sum(float v) {
  #pragma unroll
  for (int off = 32; off; off >>= 1) v += __shfl_down(v, off);
  return __shfl(v, 0);
}

// one-shot weight conversion f32 -> bf16, frag-major
__global__ __launch_bounds__(256) void cvt_weights(
    const float* __restrict__ qkv_w, const float* __restrict__ proj_w,
    const float* __restrict__ fc1_w, const float* __restrict__ fc2_w,
    short* __restrict__ ws)
{
  int idx = blockIdx.x * 256 + threadIdx.x;
  if (idx >= WTOT) return;
  int j = idx & 7, lane = (idx >> 3) & 63;
  int cl = lane & 15;
  int g  = 8 * (lane >> 4) + j;          // k offset within 32-wide slice
  float v;
  if (idx < WPROJ) {
    int ts = idx >> 9; int tile = ts / 3, s = ts - 3 * tile;
    v = qkv_w[(size_t)(16 * tile + cl) * 96 + 32 * s + g];
  } else if (idx < WFC1) {
    int ts = (idx - WPROJ) >> 9; int tile = ts / 3, s = ts - 3 * tile;
    v = proj_w[(size_t)(16 * tile + cl) * 96 + 32 * s + g];
  } else if (idx < WFC2) {
    int ts = (idx - WFC1) >> 9; int tile = ts / 3, s = ts - 3 * tile;
    v = fc1_w[(size_t)(16 * tile + cl) * 96 + 32 * s + g];
  } else {
    int ts = (idx - WFC2) >> 9; int T = ts / 3, s = ts - 3 * T;
    int nt = T >> 2, cn = T & 3;
    v = fc2_w[(size_t)(16 * nt + cl) * 384 + 96 * cn + 32 * s + g];
  }
  ws[idx] = (short)bfc(v);
}

template<bool PRE>
__global__ __launch_bounds__(256, 3) void swin_mfma_kernel(
    const float* __restrict__ x,          // [B,3136,96]
    const float* __restrict__ attn_mask,  // [64,49,49]
    const int*   __restrict__ rel_index,  // [2401]
    const float* __restrict__ n1g, const float* __restrict__ n1b,
    const float* __restrict__ qkv_w, const float* __restrict__ qkv_b,
    const float* __restrict__ rel_tab,    // [169,3]
    const float* __restrict__ proj_w, const float* __restrict__ proj_b,
    const float* __restrict__ n2g, const float* __restrict__ n2b,
    const float* __restrict__ fc1_w, const float* __restrict__ fc1_b,
    const float* __restrict__ fc2_w, const float* __restrict__ fc2_b,
    const short* __restrict__ wsw,        // bf16 weights (frag-major) or null
    float* __restrict__ out)              // [B,3136,96]
{
  __shared__ short pool[POOLN];

  const int tid  = threadIdx.x;
  const int wv   = tid >> 6;
  const int lane = tid & 63;
  const int ln   = lane & 15;
  const int gq   = lane >> 4;
  const int bw   = blockIdx.x;
  const int b    = bw >> 6, widx = bw & 63;
  const int wr   = widx >> 3, wc = widx & 7;

  const f32x4 zf = {0.f, 0.f, 0.f, 0.f};
  const int qrow = 16 * wv + ln;

  auto gbase = [&](int n) -> size_t {
    int i = n / 7, j = n - 7 * i;
    int h = wr * 7 + i + 3; if (h >= HW) h -= HW;
    int w = wc * 7 + j + 3; if (w >= HW) w -= HW;
    return ((size_t)b * (HW * HW) + (size_t)h * HW + w) * 96;
  };

  // ---- stage 1: gather (roll -3) + LN1 -> xln (bf16), zero-pad rows 49..63 ----
  for (int n = wv; n < 49; n += 4) {
    const float* src = x + gbase(n);
    float v0 = src[lane];
    float v1 = (lane < 32) ? src[64 + lane] : 0.f;
    float s  = wave_sum(v0 + v1);
    float ss = wave_sum(v0 * v0 + v1 * v1);
    float mean = s * (1.f / 96.f);
    float inv  = rsqrtf(ss * (1.f / 96.f) - mean * mean + 1e-5f);
    pool[OFF_X + n * SR + lane] = (short)bfc((v0 - mean) * inv * n1g[lane] + n1b[lane]);
    if (lane < 32)
      pool[OFF_X + n * SR + 64 + lane] =
          (short)bfc((v1 - mean) * inv * n1g[64 + lane] + n1b[64 + lane]);
  }
  for (int idx = tid; idx < 15 * 96; idx += 256) {
    int rr = idx / 96, c = idx - 96 * rr;
    pool[OFF_X + (49 + rr) * SR + c] = 0;
  }
  __syncthreads();

  // ---- stage 2: QKV. N-split across waves; A-frags held in VGPRs ----
  {
    short8 af[3][4];
    #pragma unroll
    for (int s = 0; s < 3; ++s)
      #pragma unroll
      for (int m = 0; m < 4; ++m)
        af[s][m] = *(const short8*)&pool[OFF_X + (16 * m + ln) * SR + 32 * s + 8 * gq];

    for (int t = wv; t < 18; t += 4) {
      short8 bw3[3];
      #pragma unroll
      for (int s = 0; s < 3; ++s)
        bw3[s] = wfrag<PRE>(wsw + WQKV, t * 3 + s, lane,
                            qkv_w + (size_t)(16 * t + ln) * 96 + 32 * s + 8 * gq);
      f32x4 acc[4] = {zf, zf, zf, zf};
      #pragma unroll
      for (int m = 0; m < 4; ++m)
        #pragma unroll
        for (int s = 0; s < 3; ++s)
          acc[m] = __builtin_amdgcn_mfma_f32_16x16x32_bf16(af[s][m], bw3[s], acc[m], 0, 0, 0);

      int o = 16 * t + ln;
      float bias = qkv_b[o];
      int which = t / 6;                 // 0=q 1=k 2=v
      int oo = o - 96 * which;
      int hh = oo >> 5, dd = oo & 31;
      #pragma unroll
      for (int m = 0; m < 4; ++m)
        #pragma unroll
        for (int r = 0; r < 4; ++r) {
          float v = acc[m][r] + bias;
          int token = 16 * m + 4 * gq + r;
          if (which == 0)
            pool[OFF_Q + token * SR + hh * 32 + dd] = (short)bfc(v * 0.17677669529663687f);
          else if (which == 1)
            pool[OFF_K + token * SR + hh * 32 + dd] = (short)bfc(v);
          else
            pool[OFF_V + dd * SVT + hh * 64 + token] = (short)bfc(v);
        }
    }
  }
  __syncthreads();

  // ---- stage 3: attention, head-sequential; P lives in dead xln space ----
  int   relv[4][4];
  float maskv[4][4];
  #pragma unroll
  for (int r = 0; r < 4; ++r) {
    int q  = 16 * wv + 4 * gq + r;
    int qc = q < 49 ? q : 48;
    #pragma unroll
    for (int nt = 0; nt < 4; ++nt) {
      int k = 16 * nt + ln;
      if (k < 49) {
        int qk = qc * 49 + k;
        relv[r][nt]  = rel_index[qk];
        maskv[r][nt] = attn_mask[(size_t)widx * 2401 + qk];
      } else {
        relv[r][nt]  = 0;
        maskv[r][nt] = -1e30f;
      }
    }
  }

  for (int h = 0; h < 3; ++h) {
    short8 aq = *(const short8*)&pool[OFF_Q + qrow * SR + h * 32 + 8 * gq];
    f32x4 sc[4];
    #pragma unroll
    for (int nt = 0; nt < 4; ++nt) {
      short8 bk = *(const short8*)&pool[OFF_K + (16 * nt + ln) * SR + h * 32 + 8 * gq];
      sc[nt] = __builtin_amdgcn_mfma_f32_16x16x32_bf16(aq, bk, zf, 0, 0, 0);
    }
    #pragma unroll
    for (int r = 0; r < 4; ++r) {
      float pv[4];
      #pragma unroll
      for (int nt = 0; nt < 4; ++nt)
        pv[nt] = sc[nt][r] + rel_tab[relv[r][nt] * 3 + h] + maskv[r][nt];
      float mx = fmaxf(fmaxf(pv[0], pv[1]), fmaxf(pv[2], pv[3]));
      #pragma unroll
      for (int m2 = 1; m2 < 16; m2 <<= 1) mx = fmaxf(mx, __shfl_xor(mx, m2, 64));
      float sum = 0.f;
      #pragma unroll
      for (int nt = 0; nt < 4; ++nt) { pv[nt] = __expf(pv[nt] - mx); sum += pv[nt]; }
      #pragma unroll
      for (int m2 = 1; m2 < 16; m2 <<= 1) sum += __shfl_xor(sum, m2, 64);
      float inv = 1.f / sum;
      int q = 16 * wv + 4 * gq + r;
      #pragma unroll
      for (int nt = 0; nt < 4; ++nt)
        pool[OFF_X + q * SR + 16 * nt + ln] = (short)bfc(pv[nt] * inv);
    }
    __syncthreads();

    short8 ap0 = *(const short8*)&pool[OFF_X + qrow * SR + 8 * gq];
    short8 ap1 = *(const short8*)&pool[OFF_X + qrow * SR + 32 + 8 * gq];
    #pragma unroll
    for (int nt2 = 0; nt2 < 2; ++nt2) {
      short8 bv0 = *(const short8*)&pool[OFF_V + (16 * nt2 + ln) * SVT + h * 64 + 8 * gq];
      short8 bv1 = *(const short8*)&pool[OFF_V + (16 * nt2 + ln) * SVT + h * 64 + 32 + 8 * gq];
      f32x4 o = __builtin_amdgcn_mfma_f32_16x16x32_bf16(ap0, bv0, zf, 0, 0, 0);
      o = __builtin_amdgcn_mfma_f32_16x16x32_bf16(ap1, bv1, o, 0, 0, 0);
      #pragma unroll
      for (int r = 0; r < 4; ++r) {
        int token = 16 * wv + 4 * gq + r;
        pool[OFF_Q + token * SR + h * 32 + 16 * nt2 + ln] = (short)bfc(o[r]);
      }
    }
    __syncthreads();
  }

  // ---- stage 4: proj + residual + LN2 (y in VGPRs, yn -> dead K space) ----
  float y[6][4];
  {
    short8 aa[3];
    #pragma unroll
    for (int s = 0; s < 3; ++s)
      aa[s] = *(const short8*)&pool[OFF_Q + qrow * SR + 32 * s + 8 * gq];
    #pragma unroll
    for (int nt = 0; nt < 6; ++nt) {
      f32x4 acc = zf;
      #pragma unroll
      for (int s = 0; s < 3; ++s)
        acc = __builtin_amdgcn_mfma_f32_16x16x32_bf16(
            aa[s],
            wfrag<PRE>(wsw + WPROJ, nt * 3 + s, lane,
                       proj_w + (size_t)(16 * nt + ln) * 96 + 32 * s + 8 * gq),
            acc, 0, 0, 0);
      float pb = proj_b[16 * nt + ln];
      #pragma unroll
      for (int r = 0; r < 4; ++r) y[nt][r] = acc[r] + pb;
    }
    #pragma unroll
    for (int r = 0; r < 4; ++r) {
      int token = 16 * wv + 4 * gq + r;
      if (token < 49) {
        const float* xr = x + gbase(token);
        #pragma unroll
        for (int nt = 0; nt < 6; ++nt) y[nt][r] += xr[16 * nt + ln];
      }
    }
    float g2[6], b2[6];
    #pragma unroll
    for (int nt = 0; nt < 6; ++nt) { g2[nt] = n2g[16 * nt + ln]; b2[nt] = n2b[16 * nt + ln]; }
    #pragma unroll
    for (int r = 0; r < 4; ++r) {
      float s1 = 0.f, s2 = 0.f;
      #pragma unroll
      for (int nt = 0; nt < 6; ++nt) { s1 += y[nt][r]; s2 += y[nt][r] * y[nt][r]; }
      #pragma unroll
      for (int m2 = 1; m2 < 16; m2 <<= 1) {
        s1 += __shfl_xor(s1, m2, 64);
        s2 += __shfl_xor(s2, m2, 64);
      }
      float mean = s1 * (1.f / 96.f);
      float inv  = rsqrtf(s2 * (1.f / 96.f) - mean * mean + 1e-5f);
      int token = 16 * wv + 4 * gq + r;
      #pragma unroll
      for (int nt = 0; nt < 6; ++nt)
        pool[OFF_K + token * SR + 16 * nt + ln] =
            (short)bfc((y[nt][r] - mean) * inv * g2[nt] + b2[nt]);
    }
  }
  __syncthreads();

  // ---- stage 5: MLP, 4 chunks of 96 hidden (h-chunk in dead X space) ----
  f32x4 accO[6] = {zf, zf, zf, zf, zf, zf};
  short8 ay[3];
  #pragma unroll
  for (int s = 0; s < 3; ++s)
    ay[s] = *(const short8*)&pool[OFF_K + qrow * SR + 32 * s + 8 * gq];

  for (int cn = 0; cn < 4; ++cn) {
    #pragma unroll
    for (int nt = 0; nt < 6; ++nt) {
      f32x4 acc = zf;
      #pragma unroll
      for (int s = 0; s < 3; ++s)
        acc = __builtin_amdgcn_mfma_f32_16x16x32_bf16(
            ay[s],
            wfrag<PRE>(wsw + WFC1, (6 * cn + nt) * 3 + s, lane,
                       fc1_w + (size_t)(96 * cn + 16 * nt + ln) * 96 + 32 * s + 8 * gq),
            acc, 0, 0, 0);
      float b1 = fc1_b[96 * cn + 16 * nt + ln];
      #pragma unroll
      for (int r = 0; r < 4; ++r) {
        float hv = acc[r] + b1;
        hv = 0.5f * hv * (1.f + erff(hv * 0.70710678118654752f));  // exact GELU
        int token = 16 * wv + 4 * gq + r;
        pool[OFF_X + token * SR + 16 * nt + ln] = (short)bfc(hv);
      }
    }
    __syncthreads();
    short8 ah[3];
    #pragma unroll
    for (int s = 0; s < 3; ++s)
      ah[s] = *(const short8*)&pool[OFF_X + qrow * SR + 32 * s + 8 * gq];
    #pragma unroll
    for (int nt = 0; nt < 6; ++nt) {
      #pragma unroll
      for (int s = 0; s < 3; ++s)
        accO[nt] = __builtin_amdgcn_mfma_f32_16x16x32_bf16(
            ah[s],
            wfrag<PRE>(wsw + WFC2, (nt * 4 + cn) * 3 + s, lane,
                       fc2_w + (size_t)(16 * nt + ln) * 384 + 96 * cn + 32 * s + 8 * gq),
            accO[nt], 0, 0, 0);
    }
    __syncthreads();
  }

  // ---- stage 6: out = y + mlp + fc2_b ----
  float fb[6];
  #pragma unroll
  for (int nt = 0; nt < 6; ++nt) fb[nt] = fc2_b[16 * nt + ln];
  #pragma unroll
  for (int r = 0; r < 4; ++r) {
    int token = 16 * wv + 4 * gq + r;
    if (token < 49) {
      float* dst = out + gbase(token);
      #pragma unroll
      for (int nt = 0; nt < 6; ++nt)
        dst[16 * nt + ln] = y[nt][r] + accO[nt][r] + fb[nt];
    }
  }
}

extern "C" void kernel_launch(void* const* d_in, const int* in_sizes, int n_in,
                              void* d_out, int out_size, void* d_ws, size_t ws_size,
                              hipStream_t stream) {
  const float* x         = (const float*)d_in[0];
  const float* attn_mask = (const float*)d_in[1];
  const int*   rel_index = (const int*)  d_in[2];
  const float* n1g       = (const float*)d_in[3];
  const float* n1b       = (const float*)d_in[4];
  const float* qkv_w     = (const float*)d_in[5];
  const float* qkv_b     = (const float*)d_in[6];
  const float* rel_tab   = (const float*)d_in[7];
  const float* proj_w    = (const float*)d_in[8];
  const float* proj_b    = (const float*)d_in[9];
  const float* n2g       = (const float*)d_in[10];
  const float* n2b       = (const float*)d_in[11];
  const float* fc1_w     = (const float*)d_in[12];
  const float* fc1_b     = (const float*)d_in[13];
  const float* fc2_w     = (const float*)d_in[14];
  const float* fc2_b     = (const float*)d_in[15];
  float* out = (float*)d_out;

  const int B = in_sizes[0] / (HW * HW * 96);
  const bool pre = ws_size >= (size_t)WTOT * 2;

  if (pre) {
    short* ws = (short*)d_ws;
    cvt_weights<<<(WTOT + 255) / 256, 256, 0, stream>>>(qkv_w, proj_w, fc1_w, fc2_w, ws);
    swin_mfma_kernel<true><<<B * 64, 256, 0, stream>>>(
        x, attn_mask, rel_index, n1g, n1b, qkv_w, qkv_b, rel_tab, proj_w, proj_b,
        n2g, n2b, fc1_w, fc1_b, fc2_w, fc2_b, (const short*)ws, out);
  } else {
    swin_mfma_kernel<false><<<B * 64, 256, 0, stream>>>(
        x, attn_mask, rel_index, n1g, n1b, qkv_w, qkv_b, rel_tab, proj_w, proj_b,
        n2g, n2b, fc1_w, fc1_b, fc2_w, fc2_b, (const short*)nullptr, out);
  }
}

// Round 6
// 233.761 us; speedup vs baseline: 42.8945x; 1.2681x over previous
//
#include <hip/hip_runtime.h>
#include <hip/hip_bf16.h>

// Swin block fully fused, bf16 MFMA, channel-major outputs (packed LDS writes),
// per-wave q-tile ownership (3 barriers total).
typedef __attribute__((ext_vector_type(8))) short short8;  // 8 bf16 = one A/B frag
typedef __attribute__((ext_vector_type(4))) float f32x4;   // C/D frag

constexpr int HW = 56;

// ---- LDS pool (bf16 elements). Frag-read bases 16B-aligned. ----
constexpr int SR    = 104;             // row stride for [64][96] token-major buffers
constexpr int SVT   = 200;             // row stride for vT [32][3*64]
constexpr int SP    = 72;              // row stride for P [64 q][64 keys]
constexpr int OFF_X = 0;               // [64][SR]: xln -> P (stride SP) -> fc1 h-chunk
constexpr int OFF_Q = 64 * SR;         // [64][SR]: q (cols h*32+d) -> attn-out
constexpr int OFF_K = 2 * 64 * SR;     // [64][SR]: k -> yn (LN2 out)
constexpr int OFF_V = 3 * 64 * SR;     // [32][SVT]: v^T (row d%32, col (d/32)*64+tok)
constexpr int POOLN = OFF_V + 32 * SVT;  // 26368 shorts = 52736 B -> 3 blocks/CU

// ---- d_ws layout (bf16), frag-major: [(tile*3+s)*512 + lane*8 + j] ----
constexpr int WQKV  = 0;               // 18 tiles
constexpr int WPROJ = 27648;           // 6 tiles
constexpr int WFC1  = 36864;           // 24 tiles (tile = 6*cn + nt)
constexpr int WFC2  = 73728;           // 24 tiles (tile = nt*4 + cn)
constexpr int WTOT  = 110592;          // *2B = 221184 bytes

__device__ __forceinline__ ushort bfc(float f) {
  union { __hip_bfloat16 h; ushort u; } v;
  v.h = __float2bfloat16(f);
  return v.u;
}
__device__ __forceinline__ uint pk2(float a, float b) {
  union { __hip_bfloat162 h2; uint u; } v;
  v.h2 = __float22bfloat162_rn(make_float2(a, b));
  return v.u;
}
// packed store of 4 consecutive bf16 (8B)
__device__ __forceinline__ void st4(short* p, float a, float b, float c, float d) {
  uint2 u; u.x = pk2(a, b); u.y = pk2(c, d);
  *(uint2*)p = u;
}
// fallback: 8 consecutive f32 -> bf16x8 frag (in-kernel cvt)
__device__ __forceinline__ short8 ldw8(const float* p) {
  float4 a = *(const float4*)p;
  float4 b = *(const float4*)(p + 4);
  short8 r;
  r[0] = (short)bfc(a.x); r[1] = (short)bfc(a.y); r[2] = (short)bfc(a.z); r[3] = (short)bfc(a.w);
  r[4] = (short)bfc(b.x); r[5] = (short)bfc(b.y); r[6] = (short)bfc(b.z); r[7] = (short)bfc(b.w);
  return r;
}
template<bool PRE>
__device__ __forceinline__ short8 wfrag(const short* wsb, int ts, int lane, const float* fsrc) {
  if constexpr (PRE) return *(const short8*)&wsb[(ts << 9) + lane * 8];
  else               return ldw8(fsrc);
}
__device__ __forceinline__ float wave_sum(float v) {
  #pragma unroll
  for (int off = 32; off; off >>= 1) v += __shfl_down(v, off);
  return __shfl(v, 0);
}

// one-shot weight conversion f32 -> bf16, frag-major
__global__ __launch_bounds__(256) void cvt_weights(
    const float* __restrict__ qkv_w, const float* __restrict__ proj_w,
    const float* __restrict__ fc1_w, const float* __restrict__ fc2_w,
    short* __restrict__ ws)
{
  int idx = blockIdx.x * 256 + threadIdx.x;
  if (idx >= WTOT) return;
  int j = idx & 7, lane = (idx >> 3) & 63;
  int cl = lane & 15;
  int g  = 8 * (lane >> 4) + j;          // k offset within 32-wide slice
  float v;
  if (idx < WPROJ) {
    int ts = idx >> 9; int tile = ts / 3, s = ts - 3 * tile;
    v = qkv_w[(size_t)(16 * tile + cl) * 96 + 32 * s + g];
  } else if (idx < WFC1) {
    int ts = (idx - WPROJ) >> 9; int tile = ts / 3, s = ts - 3 * tile;
    v = proj_w[(size_t)(16 * tile + cl) * 96 + 32 * s + g];
  } else if (idx < WFC2) {
    int ts = (idx - WFC1) >> 9; int tile = ts / 3, s = ts - 3 * tile;
    v = fc1_w[(size_t)(16 * tile + cl) * 96 + 32 * s + g];
  } else {
    int ts = (idx - WFC2) >> 9; int T = ts / 3, s = ts - 3 * T;
    int nt = T >> 2, cn = T & 3;
    v = fc2_w[(size_t)(16 * nt + cl) * 384 + 96 * cn + 32 * s + g];
  }
  ws[idx] = (short)bfc(v);
}

template<bool PRE>
__global__ __launch_bounds__(256, 3) void swin_mfma_kernel(
    const float* __restrict__ x,          // [B,3136,96]
    const float* __restrict__ attn_mask,  // [64,49,49]
    const int*   __restrict__ rel_index,  // [2401]
    const float* __restrict__ n1g, const float* __restrict__ n1b,
    const float* __restrict__ qkv_w, const float* __restrict__ qkv_b,
    const float* __restrict__ rel_tab,    // [169,3]
    const float* __restrict__ proj_w, const float* __restrict__ proj_b,
    const float* __restrict__ n2g, const float* __restrict__ n2b,
    const float* __restrict__ fc1_w, const float* __restrict__ fc1_b,
    const float* __restrict__ fc2_w, const float* __restrict__ fc2_b,
    const short* __restrict__ wsw,        // bf16 weights (frag-major) or null
    float* __restrict__ out)              // [B,3136,96]
{
  __shared__ alignas(16) short pool[POOLN];

  const int tid  = threadIdx.x;
  const int wv   = tid >> 6;          // wave id = q/token 16-tile owner
  const int lane = tid & 63;
  const int ln   = lane & 15;
  const int gq   = lane >> 4;
  const int bw   = blockIdx.x;
  const int b    = bw >> 6, widx = bw & 63;
  const int wr   = widx >> 3, wc = widx & 7;

  const f32x4 zf = {0.f, 0.f, 0.f, 0.f};
  const int qq = 16 * wv + ln;        // this thread's token/query row

  auto gbase = [&](int n) -> size_t {
    int i = n / 7, j = n - 7 * i;
    int h = wr * 7 + i + 3; if (h >= HW) h -= HW;
    int w = wc * 7 + j + 3; if (w >= HW) w -= HW;
    return ((size_t)b * (HW * HW) + (size_t)h * HW + w) * 96;
  };

  // ---- stage 1: gather (roll -3) + LN1 -> xln (bf16), zero-pad rows 49..63 ----
  for (int n = wv; n < 49; n += 4) {
    const float* src = x + gbase(n);
    float v0 = src[lane];
    float v1 = (lane < 32) ? src[64 + lane] : 0.f;
    float s  = wave_sum(v0 + v1);
    float ss = wave_sum(v0 * v0 + v1 * v1);
    float mean = s * (1.f / 96.f);
    float inv  = rsqrtf(ss * (1.f / 96.f) - mean * mean + 1e-5f);
    pool[OFF_X + n * SR + lane] = (short)bfc((v0 - mean) * inv * n1g[lane] + n1b[lane]);
    if (lane < 32)
      pool[OFF_X + n * SR + 64 + lane] =
          (short)bfc((v1 - mean) * inv * n1g[64 + lane] + n1b[64 + lane]);
  }
  for (int idx = tid; idx < 15 * 96; idx += 256) {
    int rr = idx / 96, c = idx - 96 * rr;
    pool[OFF_X + (49 + rr) * SR + c] = 0;
  }
  __syncthreads();

  // ---- stage 2: QKV. Q/K channel-rows (packed b64 chan writes); V token-rows
  //      (packed b64 token writes into d-major V). ----
  {
    short8 af[3][4];
    #pragma unroll
    for (int s = 0; s < 3; ++s)
      #pragma unroll
      for (int m = 0; m < 4; ++m)
        af[s][m] = *(const short8*)&pool[OFF_X + (16 * m + ln) * SR + 32 * s + 8 * gq];

    for (int t = wv; t < 18; t += 4) {
      short8 wf[3];
      #pragma unroll
      for (int s = 0; s < 3; ++s)
        wf[s] = wfrag<PRE>(wsw + WQKV, t * 3 + s, lane,
                           qkv_w + (size_t)(16 * t + ln) * 96 + 32 * s + 8 * gq);
      int which = t / 6;               // 0=q 1=k 2=v
      if (which == 2) {
        // old orientation: D[token][chan];  chan d = 16*(t-12)+ln
        int d  = 16 * (t - 12) + ln;
        float bv = qkv_b[192 + d];
        int dd = d & 31, hh = d >> 5;
        #pragma unroll
        for (int m = 0; m < 4; ++m) {
          f32x4 acc = zf;
          #pragma unroll
          for (int s = 0; s < 3; ++s)
            acc = __builtin_amdgcn_mfma_f32_16x16x32_bf16(af[s][m], wf[s], acc, 0, 0, 0);
          st4(&pool[OFF_V + dd * SVT + hh * 64 + 16 * m + 4 * gq],
              acc[0] + bv, acc[1] + bv, acc[2] + bv, acc[3] + bv);
        }
      } else {
        // new orientation: D[chan][token]; chans 16t+4gq..+3, token 16m+ln
        float4 b4 = *(const float4*)&qkv_b[16 * t + 4 * gq];
        #pragma unroll
        for (int m = 0; m < 4; ++m) {
          f32x4 acc = zf;
          #pragma unroll
          for (int s = 0; s < 3; ++s)
            acc = __builtin_amdgcn_mfma_f32_16x16x32_bf16(wf[s], af[s][m], acc, 0, 0, 0);
          int tok = 16 * m + ln;
          float v0 = acc[0] + b4.x, v1 = acc[1] + b4.y, v2 = acc[2] + b4.z, v3 = acc[3] + b4.w;
          if (which == 0) {
            const float sc_ = 0.17677669529663687f;
            st4(&pool[OFF_Q + tok * SR + 16 * t + 4 * gq], v0 * sc_, v1 * sc_, v2 * sc_, v3 * sc_);
          } else {
            st4(&pool[OFF_K + tok * SR + 16 * (t - 6) + 4 * gq], v0, v1, v2, v3);
          }
        }
      }
    }
  }
  __syncthreads();

  // ---- stage 3: attention. Wave owns q-tile wv; zero barriers (own-row P / attn-out).
  //      QK^T: D[key][q]; softmax over keys = in-thread + shfl(16,32). ----
  int   relvv[4][4];
  float maskb[4][4];
  {
    int qc = qq < 49 ? qq : 48;
    #pragma unroll
    for (int nt = 0; nt < 4; ++nt)
      #pragma unroll
      for (int r = 0; r < 4; ++r) {
        int key = 16 * nt + 4 * gq + r;
        if (key < 49) {
          int qk = qc * 49 + key;
          relvv[nt][r] = rel_index[qk];
          maskb[nt][r] = attn_mask[(size_t)widx * 2401 + qk];
        } else {
          relvv[nt][r] = 0;
          maskb[nt][r] = -1e30f;
        }
      }
  }

  for (int h = 0; h < 3; ++h) {
    short8 bq = *(const short8*)&pool[OFF_Q + qq * SR + h * 32 + 8 * gq];
    f32x4 sc[4];
    #pragma unroll
    for (int nt = 0; nt < 4; ++nt) {
      short8 ak = *(const short8*)&pool[OFF_K + (16 * nt + ln) * SR + h * 32 + 8 * gq];
      sc[nt] = __builtin_amdgcn_mfma_f32_16x16x32_bf16(ak, bq, zf, 0, 0, 0);
    }
    float pv[4][4];
    float mx = -1e30f;
    #pragma unroll
    for (int nt = 0; nt < 4; ++nt)
      #pragma unroll
      for (int r = 0; r < 4; ++r) {
        float v = sc[nt][r] + rel_tab[relvv[nt][r] * 3 + h] + maskb[nt][r];
        pv[nt][r] = v;
        mx = fmaxf(mx, v);
      }
    mx = fmaxf(mx, __shfl_xor(mx, 16, 64));
    mx = fmaxf(mx, __shfl_xor(mx, 32, 64));
    float sum = 0.f;
    #pragma unroll
    for (int nt = 0; nt < 4; ++nt)
      #pragma unroll
      for (int r = 0; r < 4; ++r) { pv[nt][r] = __expf(pv[nt][r] - mx); sum += pv[nt][r]; }
    sum += __shfl_xor(sum, 16, 64);
    sum += __shfl_xor(sum, 32, 64);
    float inv = 1.f / sum;
    #pragma unroll
    for (int nt = 0; nt < 4; ++nt)
      st4(&pool[OFF_X + qq * SP + 16 * nt + 4 * gq],
          pv[nt][0] * inv, pv[nt][1] * inv, pv[nt][2] * inv, pv[nt][3] * inv);

    // PV: D[d][q] = V^T-rows x P-rows; write attn-out token-major (packed)
    short8 bp0 = *(const short8*)&pool[OFF_X + qq * SP + 8 * gq];
    short8 bp1 = *(const short8*)&pool[OFF_X + qq * SP + 32 + 8 * gq];
    #pragma unroll
    for (int dt = 0; dt < 2; ++dt) {
      short8 av0 = *(const short8*)&pool[OFF_V + (16 * dt + ln) * SVT + h * 64 + 8 * gq];
      short8 av1 = *(const short8*)&pool[OFF_V + (16 * dt + ln) * SVT + h * 64 + 32 + 8 * gq];
      f32x4 o = __builtin_amdgcn_mfma_f32_16x16x32_bf16(av0, bp0, zf, 0, 0, 0);
      o = __builtin_amdgcn_mfma_f32_16x16x32_bf16(av1, bp1, o, 0, 0, 0);
      st4(&pool[OFF_Q + qq * SR + h * 32 + 16 * dt + 4 * gq], o[0], o[1], o[2], o[3]);
    }
  }

  // ---- stage 4: proj (D[chan][tok]) + residual + LN2 -> yn (packed) ----
  float y[6][4];
  {
    short8 ao[3];
    #pragma unroll
    for (int s = 0; s < 3; ++s)
      ao[s] = *(const short8*)&pool[OFF_Q + qq * SR + 32 * s + 8 * gq];
    #pragma unroll
    for (int nt = 0; nt < 6; ++nt) {
      f32x4 acc = zf;
      #pragma unroll
      for (int s = 0; s < 3; ++s)
        acc = __builtin_amdgcn_mfma_f32_16x16x32_bf16(
            wfrag<PRE>(wsw + WPROJ, nt * 3 + s, lane,
                       proj_w + (size_t)(16 * nt + ln) * 96 + 32 * s + 8 * gq),
            ao[s], acc, 0, 0, 0);
      float4 pb = *(const float4*)&proj_b[16 * nt + 4 * gq];
      y[nt][0] = acc[0] + pb.x; y[nt][1] = acc[1] + pb.y;
      y[nt][2] = acc[2] + pb.z; y[nt][3] = acc[3] + pb.w;
    }
    if (qq < 49) {
      const float* xr = x + gbase(qq);
      #pragma unroll
      for (int nt = 0; nt < 6; ++nt) {
        float4 xv = *(const float4*)&xr[16 * nt + 4 * gq];
        y[nt][0] += xv.x; y[nt][1] += xv.y; y[nt][2] += xv.z; y[nt][3] += xv.w;
      }
    }
    float s1 = 0.f, s2 = 0.f;
    #pragma unroll
    for (int nt = 0; nt < 6; ++nt)
      #pragma unroll
      for (int r = 0; r < 4; ++r) { s1 += y[nt][r]; s2 += y[nt][r] * y[nt][r]; }
    s1 += __shfl_xor(s1, 16, 64); s1 += __shfl_xor(s1, 32, 64);
    s2 += __shfl_xor(s2, 16, 64); s2 += __shfl_xor(s2, 32, 64);
    float mean = s1 * (1.f / 96.f);
    float inv  = rsqrtf(s2 * (1.f / 96.f) - mean * mean + 1e-5f);
    #pragma unroll
    for (int nt = 0; nt < 6; ++nt) {
      float4 g4 = *(const float4*)&n2g[16 * nt + 4 * gq];
      float4 b4 = *(const float4*)&n2b[16 * nt + 4 * gq];
      st4(&pool[OFF_K + qq * SR + 16 * nt + 4 * gq],
          (y[nt][0] - mean) * inv * g4.x + b4.x,
          (y[nt][1] - mean) * inv * g4.y + b4.y,
          (y[nt][2] - mean) * inv * g4.z + b4.z,
          (y[nt][3] - mean) * inv * g4.w + b4.w);
    }
  }
  // one barrier: h-chunk buffer below aliases P space that slower waves may still read
  __syncthreads();

  // ---- stage 5: MLP, 4 chunks of 96 hidden; h-chunk token-major in X space ----
  f32x4 accO[6] = {zf, zf, zf, zf, zf, zf};
  short8 ay[3];
  #pragma unroll
  for (int s = 0; s < 3; ++s)
    ay[s] = *(const short8*)&pool[OFF_K + qq * SR + 32 * s + 8 * gq];

  for (int cn = 0; cn < 4; ++cn) {
    #pragma unroll
    for (int nt = 0; nt < 6; ++nt) {
      f32x4 acc = zf;
      #pragma unroll
      for (int s = 0; s < 3; ++s)
        acc = __builtin_amdgcn_mfma_f32_16x16x32_bf16(
            wfrag<PRE>(wsw + WFC1, (6 * cn + nt) * 3 + s, lane,
                       fc1_w + (size_t)(96 * cn + 16 * nt + ln) * 96 + 32 * s + 8 * gq),
            ay[s], acc, 0, 0, 0);
      float4 b1 = *(const float4*)&fc1_b[96 * cn + 16 * nt + 4 * gq];
      float h0 = acc[0] + b1.x, h1 = acc[1] + b1.y, h2 = acc[2] + b1.z, h3 = acc[3] + b1.w;
      h0 = 0.5f * h0 * (1.f + erff(h0 * 0.70710678118654752f));
      h1 = 0.5f * h1 * (1.f + erff(h1 * 0.70710678118654752f));
      h2 = 0.5f * h2 * (1.f + erff(h2 * 0.70710678118654752f));
      h3 = 0.5f * h3 * (1.f + erff(h3 * 0.70710678118654752f));
      st4(&pool[OFF_X + qq * SR + 16 * nt + 4 * gq], h0, h1, h2, h3);
    }
    short8 ah[3];
    #pragma unroll
    for (int s = 0; s < 3; ++s)
      ah[s] = *(const short8*)&pool[OFF_X + qq * SR + 32 * s + 8 * gq];
    #pragma unroll
    for (int nt = 0; nt < 6; ++nt) {
      #pragma unroll
      for (int s = 0; s < 3; ++s)
        accO[nt] = __builtin_amdgcn_mfma_f32_16x16x32_bf16(
            wfrag<PRE>(wsw + WFC2, (nt * 4 + cn) * 3 + s, lane,
                       fc2_w + (size_t)(16 * nt + ln) * 384 + 96 * cn + 32 * s + 8 * gq),
            ah[s], accO[nt], 0, 0, 0);
    }
  }

  // ---- stage 6: out = y + mlp + fc2_b (float4 stores) ----
  if (qq < 49) {
    float* dst = out + gbase(qq);
    #pragma unroll
    for (int nt = 0; nt < 6; ++nt) {
      float4 fb = *(const float4*)&fc2_b[16 * nt + 4 * gq];
      float4 v;
      v.x = y[nt][0] + accO[nt][0] + fb.x;
      v.y = y[nt][1] + accO[nt][1] + fb.y;
      v.z = y[nt][2] + accO[nt][2] + fb.z;
      v.w = y[nt][3] + accO[nt][3] + fb.w;
      *(float4*)&dst[16 * nt + 4 * gq] = v;
    }
  }
}

extern "C" void kernel_launch(void* const* d_in, const int* in_sizes, int n_in,
                              void* d_out, int out_size, void* d_ws, size_t ws_size,
                              hipStream_t stream) {
  const float* x         = (const float*)d_in[0];
  const float* attn_mask = (const float*)d_in[1];
  const int*   rel_index = (const int*)  d_in[2];
  const float* n1g       = (const float*)d_in[3];
  const float* n1b       = (const float*)d_in[4];
  const float* qkv_w     = (const float*)d_in[5];
  const float* qkv_b     = (const float*)d_in[6];
  const float* rel_tab   = (const float*)d_in[7];
  const float* proj_w    = (const float*)d_in[8];
  const float* proj_b    = (const float*)d_in[9];
  const float* n2g       = (const float*)d_in[10];
  const float* n2b       = (const float*)d_in[11];
  const float* fc1_w     = (const float*)d_in[12];
  const float* fc1_b     = (const float*)d_in[13];
  const float* fc2_w     = (const float*)d_in[14];
  const float* fc2_b     = (const float*)d_in[15];
  float* out = (float*)d_out;

  const int B = in_sizes[0] / (HW * HW * 96);
  const bool pre = ws_size >= (size_t)WTOT * 2;

  if (pre) {
    short* ws = (short*)d_ws;
    cvt_weights<<<(WTOT + 255) / 256, 256, 0, stream>>>(qkv_w, proj_w, fc1_w, fc2_w, ws);
    swin_mfma_kernel<true><<<B * 64, 256, 0, stream>>>(
        x, attn_mask, rel_index, n1g, n1b, qkv_w, qkv_b, rel_tab, proj_w, proj_b,
        n2g, n2b, fc1_w, fc1_b, fc2_w, fc2_b, (const short*)ws, out);
  } else {
    swin_mfma_kernel<false><<<B * 64, 256, 0, stream>>>(
        x, attn_mask, rel_index, n1g, n1b, qkv_w, qkv_b, rel_tab, proj_w, proj_b,
        n2g, n2b, fc1_w, fc1_b, fc2_w, fc2_b, (const short*)nullptr, out);
  }
}